// Round 13
// baseline (123.293 us; speedup 1.0000x reference)
//
#include <hip/hip_runtime.h>
#include <hip/hip_bf16.h>

// ---------------------------------------------------------------------------
// FPSAttn. LSH machinery is a no-op (full attention over the permuted patch,
// inverse-permuted; rounds identical, probs==0.5).
//   out = spa*dw0 + freq*dw1
//   spa  = patch 4-head attention + Wo   (fused kernel, wave-per-head)
//   freq = FMAM; ctx via SINGLE-PASS no-max softmax; queries-softmax fused.
// Carry: (256,3) cap, XCD swizzle, b128 staging, LDS union, no-max softmax,
// M-trick (MM = Wq Wk^T) via shuffle repack, r10 FMAM config.
// Round-13 theory test: s_setprio intrinsics act as compiler scheduling
// fences -> stages serialize at source order (r12 evidence: occupancy 2 vs 3
// waves = same perf -> bound is the per-wave chain, not wave count). Change:
// REMOVE all setprio from attn; order independent stages (GT, v, z) BEFORE
// the S-stage so ~56 independent MFMAs can interleave with the repack chain.
// MFMA frag conventions (HW-verified rounds 1-12):
//   A-frag: lane(l15,l4) holds A[16*rt + l15][32*ks + 8*l4 + j], j=0..7
//   B-frag: lane holds B[32*ks + 8*l4 + j][16*ct + l15]
//   C-frag: lane holds C[16*rt + 4*l4 + r][16*ct + l15], r=0..3
// Repack identity (HW-verified): C-frag of Z (row R, col Q) -> A/B-frag of
// Z as [k=R][l15=Q] via same-l15 lane permutation (srcA/srcB/hi below).
// ---------------------------------------------------------------------------

typedef __attribute__((ext_vector_type(8))) short bf16x8;
typedef __attribute__((ext_vector_type(4))) float f32x4;
typedef __attribute__((ext_vector_type(4))) unsigned u32x4;

static __device__ __forceinline__ short f2bf(float f) {
  __hip_bfloat16 h = __float2bfloat16(f);
  return *reinterpret_cast<short*>(&h);
}
static __device__ __forceinline__ float bf2f(short s) {
  return __uint_as_float(((unsigned)(unsigned short)s) << 16);
}
// pack two f32 -> one u32 of 2 bf16 (low = a, high = b). Pure C++ (m240).
static __device__ __forceinline__ unsigned pack2bf(float a, float b) {
  return (unsigned)(unsigned short)f2bf(a) | ((unsigned)(unsigned short)f2bf(b) << 16);
}
static __device__ __forceinline__ f32x4 MFMA(bf16x8 a, bf16x8 b, f32x4 c) {
  return __builtin_amdgcn_mfma_f32_16x16x32_bf16(a, b, c, 0, 0, 0);
}

// swizzled byte offset into a [rows][64] bf16 LDS tile (128B rows)
#define LSWZ(row, bytecol) ((((row) << 7) + (bytecol)) ^ (((row) & 7) << 4))

// Repack two packed C-frag tiles (L = slab rows [0,16), H = rows [16,32))
// into an MFMA A/B-frag. pl0/pl1 = pack2bf(acc0,acc1)/(acc2,acc3).
static __device__ __forceinline__ bf16x8 repack(
    unsigned pl0, unsigned pl1, unsigned ph0, unsigned ph1,
    int srcA, int srcB, bool hi) {
  unsigned l0 = __shfl((int)pl0, srcA, 64), l1 = __shfl((int)pl1, srcA, 64);
  unsigned l2 = __shfl((int)pl0, srcB, 64), l3 = __shfl((int)pl1, srcB, 64);
  unsigned h0 = __shfl((int)ph0, srcA, 64), h1 = __shfl((int)ph1, srcA, 64);
  unsigned h2 = __shfl((int)ph0, srcB, 64), h3 = __shfl((int)ph1, srcB, 64);
  u32x4 v;
  v[0] = hi ? h0 : l0; v[1] = hi ? h1 : l1;
  v[2] = hi ? h2 : l2; v[3] = hi ? h3 : l3;
  return __builtin_bit_cast(bf16x8, v);
}

// frag of x from global [c][n]: lane supplies x[c0+j][n]
static __device__ __forceinline__ bf16x8 load_xfrag(const float* xg, int c0, int n) {
  bf16x8 r;
#pragma unroll
  for (int j = 0; j < 8; ++j) r[j] = f2bf(xg[((size_t)(c0 + j) << 16) + (size_t)n]);
  return r;
}

// ======================= W prep ============================================
// MMb: [h][c][c'] = sum_d Wq[c][48h+d] * Wk[c'][48h+d]   (bf16, row-major)
// Wvb: [h][dc][ks][lane][8] B-frag-ready Wv
// WoT2:[64 co][192 dg]  = Wo[dg][co]
// fwb/qwb: [o][c] bf16 native
__global__ __launch_bounds__(256) void prep_w(
    const float* __restrict__ Wq, const float* __restrict__ Wk,
    const float* __restrict__ Wv, const float* __restrict__ Wo,
    const float* __restrict__ fw, const float* __restrict__ qw,
    short* __restrict__ MMb, short* __restrict__ Wvb,
    short* __restrict__ WoT2, short* __restrict__ fwb, short* __restrict__ qwb)
{
  int i = blockIdx.x * 256 + threadIdx.x;
  if (i < 16384) {
    int h = i >> 12, a = (i >> 6) & 63, bb = i & 63;
    const float* wq = Wq + a * 192 + 48 * h;
    const float* wk = Wk + bb * 192 + 48 * h;
    float s = 0.f;
#pragma unroll 8
    for (int d = 0; d < 48; ++d) s += wq[d] * wk[d];
    MMb[i] = f2bf(s);
  }
  if (i < 12288) {
    int h = i / 3072, rem = i % 3072;
    int j = rem & 7, ln = (rem >> 3) & 63, dcks = rem >> 9;
    int dc = dcks >> 1, ks = dcks & 1;
    int c = 32 * ks + 8 * (ln >> 4) + j;
    int col = 48 * h + 16 * dc + (ln & 15);
    Wvb[i] = f2bf(Wv[c * 192 + col]);
  }
  if (i < 12288) {
    int co = i / 192, dg = i % 192;
    WoT2[i] = f2bf(Wo[dg * 64 + co]);
  }
  if (i < 4096) { fwb[i] = f2bf(fw[i]); qwb[i] = f2bf(qw[i]); }
}

// ================= fused attention + freq + combine ========================
__global__ __launch_bounds__(256, 3) void attn_fused(
    const float* __restrict__ x, const short* __restrict__ MMb,
    const short* __restrict__ Wvb, const short* __restrict__ WoT2,
    const short* __restrict__ qwb, const float* __restrict__ qbias,
    const short* __restrict__ ctxb16, const float* __restrict__ dw,
    float* __restrict__ out)
{
  __shared__ __align__(16) char ob_[25600];    // union: xb (first 8KB) / o-tile
  char* xb_ = ob_;

  const int tid = threadIdx.x, lane = tid & 63, w = tid >> 6;
  const int l15 = lane & 15, l4 = lane >> 4;
  const int srcA = l15 + 32 * (l4 & 1), srcB = srcA + 16;
  const bool hi = (l4 & 2) != 0;

  // XCD-aware swizzle (2048 % 8 == 0, bijective)
  const int pid0 = blockIdx.x;
  const int pid = (pid0 & 7) * 256 + (pid0 >> 3);
  const int b = pid >> 10, prem = pid & 1023;
  const int y0 = (prem >> 5) << 3, x0 = (prem & 31) << 3;
  const float* xg = x + ((size_t)b << 22);

  // ---- stage x -> xb[t][c] via 2x ds_write_b128 ----
#pragma unroll
  for (int k = 0; k < 2; ++k) {
    int idx = tid + (k << 8);
    int t = idx & 63, c0 = (idx >> 6) << 3;
    const size_t pos = (size_t)((y0 + (t >> 3)) * 256 + x0 + (t & 7));
    bf16x8 v;
#pragma unroll
    for (int j = 0; j < 8; ++j) v[j] = f2bf(xg[((size_t)(c0 + j) << 16) + pos]);
    *(bf16x8*)(xb_ + LSWZ(t, c0 * 2)) = v;
  }
  __syncthreads();

  const int h = w;   // wave = head

  // xb row frags (rows 16*i + l15): shared by GT-B, S-B, v-A; z uses [w]
  bf16x8 Bx[4][2];
#pragma unroll
  for (int i = 0; i < 4; ++i) {
    Bx[i][0] = *(const bf16x8*)(xb_ + LSWZ(16 * i + l15, 16 * l4));
    Bx[i][1] = *(const bf16x8*)(xb_ + LSWZ(16 * i + l15, 64 + 16 * l4));
  }

  // ---- GT[c][u] = MM_h @ x^T  (C: row=c, col=u) ----
  unsigned gtpk[4][4][2];   // [rt = c-tile][ct = u-tile][pair]
  {
    const short* MMh = MMb + (h << 12);
    bf16x8 am[4][2];
#pragma unroll
    for (int rt = 0; rt < 4; ++rt)
#pragma unroll
      for (int ks = 0; ks < 2; ++ks)
        am[rt][ks] = *(const bf16x8*)(MMh + (16 * rt + l15) * 64 + 32 * ks + 8 * l4);
#pragma unroll
    for (int ct = 0; ct < 4; ++ct) {
#pragma unroll
      for (int rt = 0; rt < 4; ++rt) {
        f32x4 acc = (f32x4)0.f;
        acc = MFMA(am[rt][0], Bx[ct][0], acc);
        acc = MFMA(am[rt][1], Bx[ct][1], acc);
        gtpk[rt][ct][0] = pack2bf(acc[0], acc[1]);
        gtpk[rt][ct][1] = pack2bf(acc[2], acc[3]);
      }
    }
  }

  // ---- v[u][d] = sum_c x[u][c] Wv[c][d]  (independent of GT; scheduler
  //      can interleave these MFMAs with the GA repack chain below) ----
  unsigned vpk[4][3][2];
  {
    const short* Wvh = Wvb + h * 3072;
    bf16x8 bv[3][2];
#pragma unroll
    for (int dc = 0; dc < 3; ++dc)
#pragma unroll
      for (int ks = 0; ks < 2; ++ks)
        bv[dc][ks] = *(const bf16x8*)(Wvh + ((dc * 2 + ks) * 64 + lane) * 8);
#pragma unroll
    for (int ur = 0; ur < 4; ++ur) {
#pragma unroll
      for (int dc = 0; dc < 3; ++dc) {
        f32x4 acc = (f32x4)0.f;
        acc = MFMA(Bx[ur][0], bv[dc][0], acc);
        acc = MFMA(Bx[ur][1], bv[dc][1], acc);
        vpk[ur][dc][0] = pack2bf(acc[0], acc[1]);
        vpk[ur][dc][1] = pack2bf(acc[2], acc[3]);
      }
    }
  }

  // ---- z logits for t-strip w (NO-MAX; independent of GT/S) ----
  unsigned pzpk[4][2];
  float invz;
  {
    float zs = 0.f;
#pragma unroll
    for (int orr = 0; orr < 4; ++orr) {
      bf16x8 a0 = *(const bf16x8*)(qwb + (16 * orr + l15) * 64 + 8 * l4);
      bf16x8 a1 = *(const bf16x8*)(qwb + (16 * orr + l15) * 64 + 32 + 8 * l4);
      f32x4 acc;
#pragma unroll
      for (int r = 0; r < 4; ++r) acc[r] = qbias[16 * orr + 4 * l4 + r];
      acc = MFMA(a0, Bx[w][0], acc);
      acc = MFMA(a1, Bx[w][1], acc);
      float e0 = __expf(acc[0]), e1 = __expf(acc[1]);
      float e2 = __expf(acc[2]), e3 = __expf(acc[3]);
      zs += (e0 + e1) + (e2 + e3);
      pzpk[orr][0] = pack2bf(e0, e1);
      pzpk[orr][1] = pack2bf(e2, e3);
    }
    zs += __shfl_xor(zs, 16, 64);
    zs += __shfl_xor(zs, 32, 64);
    invz = 1.f / zs;
  }

  // ---- S^T[u][t] = G @ x^T: A = repack(GT), B = natural xb frag.
  //      NO-MAX softmax; 1/s folded into the PV epilogue ----
  unsigned ppk[4][4][2];
  float invs[4];
  {
    bf16x8 GA[4][2];
#pragma unroll
    for (int ur = 0; ur < 4; ++ur) {
      GA[ur][0] = repack(gtpk[0][ur][0], gtpk[0][ur][1], gtpk[1][ur][0], gtpk[1][ur][1], srcA, srcB, hi);
      GA[ur][1] = repack(gtpk[2][ur][0], gtpk[2][ur][1], gtpk[3][ur][0], gtpk[3][ur][1], srcA, srcB, hi);
    }
    float esum[4] = {0.f, 0.f, 0.f, 0.f};
#pragma unroll
    for (int tt = 0; tt < 4; ++tt) {
#pragma unroll
      for (int ur = 0; ur < 4; ++ur) {
        f32x4 acc = (f32x4)0.f;
        acc = MFMA(GA[ur][0], Bx[tt][0], acc);
        acc = MFMA(GA[ur][1], Bx[tt][1], acc);
        // |S| <~ 1.2 -> exp overflow-impossible
        float e0 = __expf(acc[0]), e1 = __expf(acc[1]);
        float e2 = __expf(acc[2]), e3 = __expf(acc[3]);
        esum[tt] += (e0 + e1) + (e2 + e3);
        ppk[ur][tt][0] = pack2bf(e0, e1);
        ppk[ur][tt][1] = pack2bf(e2, e3);
      }
    }
#pragma unroll
    for (int tt = 0; tt < 4; ++tt) {
      esum[tt] += __shfl_xor(esum[tt], 16, 64);
      esum[tt] += __shfl_xor(esum[tt], 32, 64);
      invs[tt] = 1.f / esum[tt];
    }
  }
  __syncthreads();   // all xb reads done; union buffer becomes o-tile

  // ---- oT = vT @ e^T, scaled by invs[tt] at pack -> ob[t][48h+dloc] ----
  {
    bf16x8 Bp[4][2];
#pragma unroll
    for (int tt = 0; tt < 4; ++tt) {
      Bp[tt][0] = repack(ppk[0][tt][0], ppk[0][tt][1], ppk[1][tt][0], ppk[1][tt][1], srcA, srcB, hi);
      Bp[tt][1] = repack(ppk[2][tt][0], ppk[2][tt][1], ppk[3][tt][0], ppk[3][tt][1], srcA, srcB, hi);
    }
#pragma unroll
    for (int dr = 0; dr < 3; ++dr) {
      bf16x8 A0 = repack(vpk[0][dr][0], vpk[0][dr][1], vpk[1][dr][0], vpk[1][dr][1], srcA, srcB, hi);
      bf16x8 A1 = repack(vpk[2][dr][0], vpk[2][dr][1], vpk[3][dr][0], vpk[3][dr][1], srcA, srcB, hi);
#pragma unroll
      for (int tt = 0; tt < 4; ++tt) {
        f32x4 acc = (f32x4)0.f;
        acc = MFMA(A0, Bp[tt][0], acc);
        acc = MFMA(A1, Bp[tt][1], acc);
        const float iv = invs[tt];     // col t = 16tt+l15 -> this lane's sum
        const int row = 16 * tt + l15;
        const int col = 48 * h + 16 * dr + 4 * l4;
        *(unsigned*)(ob_ + row * 400 + col * 2)     = pack2bf(acc[0] * iv, acc[1] * iv);
        *(unsigned*)(ob_ + row * 400 + col * 2 + 4) = pack2bf(acc[2] * iv, acc[3] * iv);
      }
    }
  }
  __syncthreads();

  // ---- outT[co][t] = WoT2 @ o_all (K=192); freqT = ctx @ ez; combine ----
  {
    f32x4 ot[4], ft[4];
#pragma unroll
    for (int kr = 0; kr < 4; ++kr) { ot[kr] = (f32x4)0.f; ft[kr] = (f32x4)0.f; }
#pragma unroll
    for (int ks = 0; ks < 6; ++ks) {
      bf16x8 bo = *(const bf16x8*)(ob_ + (16 * w + l15) * 400 + 64 * ks + 16 * l4);
#pragma unroll
      for (int kr = 0; kr < 4; ++kr) {
        bf16x8 a = *(const bf16x8*)(WoT2 + (16 * kr + l15) * 192 + 32 * ks + 8 * l4);
        ot[kr] = MFMA(a, bo, ot[kr]);
      }
    }
    {
      bf16x8 Bz0 = repack(pzpk[0][0], pzpk[0][1], pzpk[1][0], pzpk[1][1], srcA, srcB, hi);
      bf16x8 Bz1 = repack(pzpk[2][0], pzpk[2][1], pzpk[3][0], pzpk[3][1], srcA, srcB, hi);
      const short* cb = ctxb16 + ((size_t)b << 12);
#pragma unroll
      for (int kr = 0; kr < 4; ++kr) {
        bf16x8 a0 = *(const bf16x8*)(cb + (16 * kr + l15) * 64 + 8 * l4);
        bf16x8 a1 = *(const bf16x8*)(cb + (16 * kr + l15) * 64 + 32 + 8 * l4);
        ft[kr] = MFMA(a0, Bz0, ft[kr]);
        ft[kr] = MFMA(a1, Bz1, ft[kr]);
      }
    }
    const int t = 16 * w + l15;
    const size_t nbase = (size_t)((y0 + (t >> 3)) * 256 + x0 + (t & 7));
    float* og = out + ((size_t)b << 22);
#pragma unroll
    for (int kr = 0; kr < 4; ++kr)
#pragma unroll
      for (int r = 0; r < 4; ++r) {
        const int co = 16 * kr + 4 * l4 + r;
        og[((size_t)co << 16) + nbase] =
            ot[kr][r] * dw[2 * co] + ft[kr][r] * invz * dw[2 * co + 1];
      }
  }
}

// ========== FMAM single-pass: ctx partials + esum (no-max softmax) =========
// r10 config: chunk = 256 n, grid 512; cred bf16.
__global__ __launch_bounds__(256) void fmam_ctx1(
    const float* __restrict__ x, const short* __restrict__ fwb,
    const float* __restrict__ fb, float* __restrict__ ctxpart,
    float* __restrict__ epart)
{
  __shared__ short cred16[4][64 * 68];   // [wave][o*68 + c] bf16
  __shared__ float ered[4][64];
  const int tid = threadIdx.x, lane = tid & 63, w = tid >> 6;
  const int l15 = lane & 15, l4 = lane >> 4;
  const int srcA = l15 + 32 * (l4 & 1), srcB = srcA + 16;
  const bool hi = (l4 & 2) != 0;
  const int chunk = blockIdx.x, b = blockIdx.y;
  const float* xg = x + ((size_t)b << 22);
  const int n0 = (chunk << 8) + (w << 6);

  bf16x8 Bfw[4][2];
#pragma unroll
  for (int ct = 0; ct < 4; ++ct)
#pragma unroll
    for (int ks = 0; ks < 2; ++ks)
      Bfw[ct][ks] = *(const bf16x8*)(fwb + (16 * ct + l15) * 64 + 32 * ks + 8 * l4);
  float fbl[4];
#pragma unroll
  for (int ct = 0; ct < 4; ++ct) fbl[ct] = fb[16 * ct + l15];

  f32x4 acc[4][4];
#pragma unroll
  for (int i = 0; i < 4; ++i)
#pragma unroll
    for (int j = 0; j < 4; ++j) acc[i][j] = (f32x4)0.f;
  float esum[4] = {0.f, 0.f, 0.f, 0.f};

#pragma unroll
  for (int ns = 0; ns < 2; ++ns) {
    const int nb = n0 + 32 * ns;
    bf16x8 axT[2][2];
#pragma unroll
    for (int rt = 0; rt < 2; ++rt)
#pragma unroll
      for (int ks = 0; ks < 2; ++ks)
        axT[rt][ks] = load_xfrag(xg, 32 * ks + 8 * l4, nb + 16 * rt + l15);
    unsigned pl[4][2][2];
#pragma unroll
    for (int rt = 0; rt < 2; ++rt)
#pragma unroll
      for (int ct = 0; ct < 4; ++ct) {
        f32x4 yt = (f32x4)(fbl[ct]);
        yt = MFMA(axT[rt][0], Bfw[ct][0], yt);
        yt = MFMA(axT[rt][1], Bfw[ct][1], yt);
        float e0 = __expf(yt[0]), e1 = __expf(yt[1]);
        float e2 = __expf(yt[2]), e3 = __expf(yt[3]);
        esum[ct] += (e0 + e1) + (e2 + e3);
        pl[ct][rt][0] = pack2bf(e0, e1);
        pl[ct][rt][1] = pack2bf(e2, e3);
      }
    bf16x8 axc[4];
#pragma unroll
    for (int rt2 = 0; rt2 < 4; ++rt2) {
      const float* xr = xg + ((size_t)(16 * rt2 + l15) << 16) + nb + 8 * l4;
      const float4 a4 = *(const float4*)xr;
      const float4 b4 = *(const float4*)(xr + 4);
      bf16x8 f;
      f[0] = f2bf(a4.x); f[1] = f2bf(a4.y); f[2] = f2bf(a4.z); f[3] = f2bf(a4.w);
      f[4] = f2bf(b4.x); f[5] = f2bf(b4.y); f[6] = f2bf(b4.z); f[7] = f2bf(b4.w);
      axc[rt2] = f;
    }
#pragma unroll
    for (int ct = 0; ct < 4; ++ct) {
      bf16x8 Bp = repack(pl[ct][0][0], pl[ct][0][1], pl[ct][1][0], pl[ct][1][1],
                         srcA, srcB, hi);
#pragma unroll
      for (int rt2 = 0; rt2 < 4; ++rt2)
        acc[rt2][ct] = MFMA(axc[rt2], Bp, acc[rt2][ct]);
    }
  }
#pragma unroll
  for (int ct = 0; ct < 4; ++ct) {
    esum[ct] += __shfl_xor(esum[ct], 16, 64);
    esum[ct] += __shfl_xor(esum[ct], 32, 64);
  }
  if (l4 == 0) {
#pragma unroll
    for (int ct = 0; ct < 4; ++ct) ered[w][16 * ct + l15] = esum[ct];
  }
#pragma unroll
  for (int ct = 0; ct < 4; ++ct)
#pragma unroll
    for (int rt2 = 0; rt2 < 4; ++rt2) {
      uint2 pr;
      pr.x = pack2bf(acc[rt2][ct][0], acc[rt2][ct][1]);
      pr.y = pack2bf(acc[rt2][ct][2], acc[rt2][ct][3]);
      *(uint2*)&cred16[w][(16 * ct + l15) * 68 + 16 * rt2 + 4 * l4] = pr;
    }
  __syncthreads();
  float* cp = ctxpart + ((((size_t)b << 8) + chunk) << 12);
  for (int i = tid; i < 4096; i += 256) {
    const int o = i >> 6, c = i & 63;
    const int li = o * 68 + c;
    cp[i] = (bf2f(cred16[0][li]) + bf2f(cred16[1][li])) +
            (bf2f(cred16[2][li]) + bf2f(cred16[3][li]));
  }
  if (tid < 64)
    epart[(((b << 8) + chunk) << 6) + tid] =
        (ered[0][tid] + ered[1][tid]) + (ered[2][tid] + ered[3][tid]);
}

// ====== reduce ctx partials over chunks, divide by esum, emit bf16 ========
__global__ __launch_bounds__(256) void fmam_ctxreduce2(
    const float* __restrict__ ctxpart, const float* __restrict__ epart,
    short* __restrict__ ctxb16)
{
  __shared__ float red[256];
  __shared__ float invs;
  const int bo = blockIdx.x;           // b*64 + o (128 blocks)
  const int b = bo >> 6, o = bo & 63;
  const int tid = threadIdx.x;
  red[tid] = epart[(((b << 8) + tid) << 6) + o];
  __syncthreads();
  if (tid < 64) {
    float v = red[tid] + red[tid + 64] + red[tid + 128] + red[tid + 192];
#pragma unroll
    for (int m = 1; m <= 32; m <<= 1) v += __shfl_xor(v, m, 64);
    if (tid == 0) invs = 1.f / v;
  }
  __syncthreads();
  const float inv = invs;
  const int c = tid & 63, cg = tid >> 6;
  const float* p = ctxpart + ((size_t)b << 20) + (o << 6) + c;
  float s = 0.f;
  for (int ch = cg * 64; ch < cg * 64 + 64; ++ch) s += p[(size_t)ch << 12];
  __syncthreads();
  red[tid] = s;
  __syncthreads();
  if (tid < 64) {
    const float v = red[tid] + red[tid + 64] + red[tid + 128] + red[tid + 192];
    ctxb16[(bo << 6) + tid] = f2bf(v * inv);
  }
}

// ===========================================================================
extern "C" void kernel_launch(void* const* d_in, const int* in_sizes, int n_in,
                              void* d_out, int out_size, void* d_ws, size_t ws_size,
                              hipStream_t stream) {
  const float* x  = (const float*)d_in[0];
  const float* Wq = (const float*)d_in[1];
  const float* Wk = (const float*)d_in[2];
  const float* Wv = (const float*)d_in[3];
  const float* Wo = (const float*)d_in[4];
  const float* qw = (const float*)d_in[7];
  const float* qb = (const float*)d_in[8];
  const float* fw = (const float*)d_in[9];
  const float* fb = (const float*)d_in[10];
  const float* dw = (const float*)d_in[11];
  float* out = (float*)d_out;

  float* ws = (float*)d_ws;
  float* ctxpart = ws;                       // 8MB
  float* epart   = ctxpart + 2097152;        // 128KB
  short* wbuf    = (short*)(epart + 32768);
  short* MMb  = wbuf;                        // 16384
  short* Wvb  = MMb + 16384;                 // 12288
  short* WoT2 = Wvb + 12288;                 // 12288
  short* fwb  = WoT2 + 12288;                // 4096
  short* qwb  = fwb + 4096;                  // 4096
  short* ctxb16 = qwb + 4096;                // 8192

  hipLaunchKernelGGL(prep_w, dim3(64), dim3(256), 0, stream,
                     Wq, Wk, Wv, Wo, fw, qw, MMb, Wvb, WoT2, fwb, qwb);
  hipLaunchKernelGGL(fmam_ctx1, dim3(256, 2), dim3(256), 0, stream,
                     x, fwb, fb, ctxpart, epart);
  hipLaunchKernelGGL(fmam_ctxreduce2, dim3(128), dim3(256), 0, stream,
                     ctxpart, epart, ctxb16);
  hipLaunchKernelGGL(attn_fused, dim3(2048), dim3(256), 0, stream,
                     x, MMb, Wvb, WoT2, qwb, qb, ctxb16, dw, out);
}

// Round 14
// 94.166 us; speedup vs baseline: 1.3093x; 1.3093x over previous
//
#include <hip/hip_runtime.h>
#include <hip/hip_bf16.h>

// ---------------------------------------------------------------------------
// FPSAttn. LSH machinery is a no-op (full attention over the permuted patch,
// inverse-permuted; rounds identical, probs==0.5).
//   out = spa*dw0 + freq*dw1
//   spa  = patch 4-head attention + Wo   (fused kernel, wave-per-head)
//   freq = FMAM; ctx via SINGLE-PASS no-max softmax; queries-softmax fused.
// Round-14 = best-of-record assembly:
//   attn  = r11 version (Wt3 q/k, no-max softmax, setprio T5, (256,3) cap,
//           XCD swizzle, b128 staging, LDS union) — 70.7-71.6us measured.
//           (r12 M-trick +2us, r13 setprio-removal +17us: both dropped.)
//   FMAM  = r10 config (chunk 256, grid 512, bf16 cred) with TWO fixes:
//           chunk partials stored bf16 (8->4MB round-trip) and the reduce
//           widened 128 -> 512+128 blocks (was 0.5 blocks/CU, ~10us).
// MFMA frag conventions (HW-verified rounds 1-13):
//   A-frag: lane(l15,l4) holds A[16*rt + l15][32*ks + 8*l4 + j], j=0..7
//   B-frag: lane holds B[32*ks + 8*l4 + j][16*ct + l15]
//   C-frag: lane holds C[16*rt + 4*l4 + r][16*ct + l15], r=0..3
// Repack identity (HW-verified): C-frag of Z (row R, col Q) -> A/B-frag of
// Z as [k=R][l15=Q] via same-l15 lane permutation (srcA/srcB/hi below).
// ---------------------------------------------------------------------------

typedef __attribute__((ext_vector_type(8))) short bf16x8;
typedef __attribute__((ext_vector_type(4))) float f32x4;
typedef __attribute__((ext_vector_type(4))) unsigned u32x4;

static __device__ __forceinline__ short f2bf(float f) {
  __hip_bfloat16 h = __float2bfloat16(f);
  return *reinterpret_cast<short*>(&h);
}
static __device__ __forceinline__ float bf2f(short s) {
  return __uint_as_float(((unsigned)(unsigned short)s) << 16);
}
// pack two f32 -> one u32 of 2 bf16 (low = a, high = b). Pure C++ (m240).
static __device__ __forceinline__ unsigned pack2bf(float a, float b) {
  return (unsigned)(unsigned short)f2bf(a) | ((unsigned)(unsigned short)f2bf(b) << 16);
}
static __device__ __forceinline__ f32x4 MFMA(bf16x8 a, bf16x8 b, f32x4 c) {
  return __builtin_amdgcn_mfma_f32_16x16x32_bf16(a, b, c, 0, 0, 0);
}

// swizzled byte offset into a [rows][64] bf16 LDS tile (128B rows)
#define LSWZ(row, bytecol) ((((row) << 7) + (bytecol)) ^ (((row) & 7) << 4))

// Repack two packed C-frag tiles (L = slab rows [0,16), H = rows [16,32))
// into an MFMA A/B-frag. pl0/pl1 = pack2bf(acc0,acc1)/(acc2,acc3).
static __device__ __forceinline__ bf16x8 repack(
    unsigned pl0, unsigned pl1, unsigned ph0, unsigned ph1,
    int srcA, int srcB, bool hi) {
  unsigned l0 = __shfl((int)pl0, srcA, 64), l1 = __shfl((int)pl1, srcA, 64);
  unsigned l2 = __shfl((int)pl0, srcB, 64), l3 = __shfl((int)pl1, srcB, 64);
  unsigned h0 = __shfl((int)ph0, srcA, 64), h1 = __shfl((int)ph1, srcA, 64);
  unsigned h2 = __shfl((int)ph0, srcB, 64), h3 = __shfl((int)ph1, srcB, 64);
  u32x4 v;
  v[0] = hi ? h0 : l0; v[1] = hi ? h1 : l1;
  v[2] = hi ? h2 : l2; v[3] = hi ? h3 : l3;
  return __builtin_bit_cast(bf16x8, v);
}
// variant: H tile is all-zero (K-padding)
static __device__ __forceinline__ bf16x8 repack1(
    unsigned pl0, unsigned pl1, int srcA, int srcB, bool hi) {
  unsigned l0 = __shfl((int)pl0, srcA, 64), l1 = __shfl((int)pl1, srcA, 64);
  unsigned l2 = __shfl((int)pl0, srcB, 64), l3 = __shfl((int)pl1, srcB, 64);
  u32x4 v;
  v[0] = hi ? 0u : l0; v[1] = hi ? 0u : l1;
  v[2] = hi ? 0u : l2; v[3] = hi ? 0u : l3;
  return __builtin_bit_cast(bf16x8, v);
}

// frag of x from global [c][n]: lane supplies x[c0+j][n]
static __device__ __forceinline__ bf16x8 load_xfrag(const float* xg, int c0, int n) {
  bf16x8 r;
#pragma unroll
  for (int j = 0; j < 8; ++j) r[j] = f2bf(xg[((size_t)(c0 + j) << 16) + (size_t)n]);
  return r;
}

// ======================= W prep ============================================
// Wt3: [2][192][64]  WqT,WkT (row = global dim, col = c)
// Wvb: [h][dc][ks][lane][8] B-frag-ready Wv
// WoT2:[64 co][192 dg]  = Wo[dg][co]
// fwb/qwb: [o][c] bf16 native
__global__ __launch_bounds__(256) void prep_w(
    const float* __restrict__ Wq, const float* __restrict__ Wk,
    const float* __restrict__ Wv, const float* __restrict__ Wo,
    const float* __restrict__ fw, const float* __restrict__ qw,
    short* __restrict__ Wt3, short* __restrict__ Wvb,
    short* __restrict__ WoT2, short* __restrict__ fwb, short* __restrict__ qwb)
{
  int i = blockIdx.x * 256 + threadIdx.x;
  if (i < 24576) {
    int m = i / 12288, rem = i % 12288;
    int r = rem >> 6, c = rem & 63;
    const float* W = m ? Wk : Wq;
    Wt3[i] = f2bf(W[c * 192 + r]);
  }
  if (i < 12288) {
    int h = i / 3072, rem = i % 3072;
    int j = rem & 7, ln = (rem >> 3) & 63, dcks = rem >> 9;
    int dc = dcks >> 1, ks = dcks & 1;
    int c = 32 * ks + 8 * (ln >> 4) + j;
    int col = 48 * h + 16 * dc + (ln & 15);
    Wvb[i] = f2bf(Wv[c * 192 + col]);
  }
  if (i < 12288) {
    int co = i / 192, dg = i % 192;
    WoT2[i] = f2bf(Wo[dg * 64 + co]);
  }
  if (i < 4096) { fwb[i] = f2bf(fw[i]); qwb[i] = f2bf(qw[i]); }
}

// ================= fused attention + freq + combine (r11 best) =============
__global__ __launch_bounds__(256, 3) void attn_fused(
    const float* __restrict__ x, const short* __restrict__ Wt3,
    const short* __restrict__ Wvb, const short* __restrict__ WoT2,
    const short* __restrict__ qwb, const float* __restrict__ qbias,
    const short* __restrict__ ctxb16, const float* __restrict__ dw,
    float* __restrict__ out)
{
  __shared__ __align__(16) char ob_[25600];    // union: xb (first 8KB) / o-tile
  char* xb_ = ob_;

  const int tid = threadIdx.x, lane = tid & 63, w = tid >> 6;
  const int l15 = lane & 15, l4 = lane >> 4;
  const int srcA = l15 + 32 * (l4 & 1), srcB = srcA + 16;
  const bool hi = (l4 & 2) != 0;

  // XCD-aware swizzle (2048 % 8 == 0, bijective)
  const int pid0 = blockIdx.x;
  const int pid = (pid0 & 7) * 256 + (pid0 >> 3);
  const int b = pid >> 10, prem = pid & 1023;
  const int y0 = (prem >> 5) << 3, x0 = (prem & 31) << 3;
  const float* xg = x + ((size_t)b << 22);

  // ---- stage x -> xb[t][c] via 2x ds_write_b128 ----
#pragma unroll
  for (int k = 0; k < 2; ++k) {
    int idx = tid + (k << 8);
    int t = idx & 63, c0 = (idx >> 6) << 3;
    const size_t pos = (size_t)((y0 + (t >> 3)) * 256 + x0 + (t & 7));
    bf16x8 v;
#pragma unroll
    for (int j = 0; j < 8; ++j) v[j] = f2bf(xg[((size_t)(c0 + j) << 16) + pos]);
    *(bf16x8*)(xb_ + LSWZ(t, c0 * 2)) = v;
  }
  __syncthreads();

  const int h = w;   // wave = head

  // ---- qT, kT:  ZT[d][t] = sum_c WT[d][c] x[t][c]  (C: col=t, row=d) ----
  unsigned qpk[3][4][2], kpk[3][4][2];
#pragma unroll
  for (int m = 0; m < 2; ++m) {
    const short* WT = Wt3 + m * 12288 + (48 * h) * 64;
    bf16x8 a[3][2];
#pragma unroll
    for (int rp = 0; rp < 3; ++rp)
#pragma unroll
      for (int ks = 0; ks < 2; ++ks)
        a[rp][ks] = *(const bf16x8*)(WT + (16 * rp + l15) * 64 + 32 * ks + 8 * l4);
    __builtin_amdgcn_s_setprio(1);
#pragma unroll
    for (int cq = 0; cq < 4; ++cq) {
      bf16x8 b0 = *(const bf16x8*)(xb_ + LSWZ(16 * cq + l15, 16 * l4));
      bf16x8 b1 = *(const bf16x8*)(xb_ + LSWZ(16 * cq + l15, 64 + 16 * l4));
#pragma unroll
      for (int rp = 0; rp < 3; ++rp) {
        f32x4 acc = (f32x4)0.f;
        acc = MFMA(a[rp][0], b0, acc);
        acc = MFMA(a[rp][1], b1, acc);
        unsigned* dst = m ? kpk[rp][cq] : qpk[rp][cq];
        dst[0] = pack2bf(acc[0], acc[1]);
        dst[1] = pack2bf(acc[2], acc[3]);
      }
    }
    __builtin_amdgcn_s_setprio(0);
  }

  // ---- S^T = k @ qT (K=48); NO-MAX softmax: e=exp(S) packed immediately,
  //      row-sums reduced after; 1/s folded into the PV epilogue ----
  unsigned ppk[4][4][2];
  float invs[4];
  {
    bf16x8 Bq[4][2];
#pragma unroll
    for (int tt = 0; tt < 4; ++tt) {
      Bq[tt][0] = repack(qpk[0][tt][0], qpk[0][tt][1], qpk[1][tt][0], qpk[1][tt][1], srcA, srcB, hi);
      Bq[tt][1] = repack1(qpk[2][tt][0], qpk[2][tt][1], srcA, srcB, hi);
    }
    float esum[4] = {0.f, 0.f, 0.f, 0.f};
#pragma unroll
    for (int ur = 0; ur < 4; ++ur) {
      bf16x8 A0 = repack(kpk[0][ur][0], kpk[0][ur][1], kpk[1][ur][0], kpk[1][ur][1], srcA, srcB, hi);
      bf16x8 A1 = repack1(kpk[2][ur][0], kpk[2][ur][1], srcA, srcB, hi);
      __builtin_amdgcn_s_setprio(1);
#pragma unroll
      for (int tt = 0; tt < 4; ++tt) {
        f32x4 acc = (f32x4)0.f;
        acc = MFMA(A0, Bq[tt][0], acc);
        acc = MFMA(A1, Bq[tt][1], acc);
        // |S| <~ 1.2 -> exp overflow-impossible
        float e0 = __expf(acc[0]), e1 = __expf(acc[1]);
        float e2 = __expf(acc[2]), e3 = __expf(acc[3]);
        esum[tt] += (e0 + e1) + (e2 + e3);
        ppk[ur][tt][0] = pack2bf(e0, e1);
        ppk[ur][tt][1] = pack2bf(e2, e3);
      }
      __builtin_amdgcn_s_setprio(0);
    }
#pragma unroll
    for (int tt = 0; tt < 4; ++tt) {
      esum[tt] += __shfl_xor(esum[tt], 16, 64);
      esum[tt] += __shfl_xor(esum[tt], 32, 64);
      invs[tt] = 1.f / esum[tt];
    }
  }

  // ---- v[u][d] = sum_c x[u][c] Wv[c][d]  (C: col=d, row=u) ----
  unsigned vpk[4][3][2];
  {
    const short* Wvh = Wvb + h * 3072;
    bf16x8 bv[3][2];
#pragma unroll
    for (int dc = 0; dc < 3; ++dc)
#pragma unroll
      for (int ks = 0; ks < 2; ++ks)
        bv[dc][ks] = *(const bf16x8*)(Wvh + ((dc * 2 + ks) * 64 + lane) * 8);
    __builtin_amdgcn_s_setprio(1);
#pragma unroll
    for (int ur = 0; ur < 4; ++ur) {
      bf16x8 a0 = *(const bf16x8*)(xb_ + LSWZ(16 * ur + l15, 16 * l4));
      bf16x8 a1 = *(const bf16x8*)(xb_ + LSWZ(16 * ur + l15, 64 + 16 * l4));
#pragma unroll
      for (int dc = 0; dc < 3; ++dc) {
        f32x4 acc = (f32x4)0.f;
        acc = MFMA(a0, bv[dc][0], acc);
        acc = MFMA(a1, bv[dc][1], acc);
        vpk[ur][dc][0] = pack2bf(acc[0], acc[1]);
        vpk[ur][dc][1] = pack2bf(acc[2], acc[3]);
      }
    }
    __builtin_amdgcn_s_setprio(0);
  }

  // ---- z logits for t-strip w (NO-MAX): ez packed, 1/zs folded into ft ----
  unsigned pzpk[4][2];
  float invz;
  {
    bf16x8 xz0 = *(const bf16x8*)(xb_ + LSWZ(16 * w + l15, 16 * l4));
    bf16x8 xz1 = *(const bf16x8*)(xb_ + LSWZ(16 * w + l15, 64 + 16 * l4));
    float zs = 0.f;
#pragma unroll
    for (int orr = 0; orr < 4; ++orr) {
      bf16x8 a0 = *(const bf16x8*)(qwb + (16 * orr + l15) * 64 + 8 * l4);
      bf16x8 a1 = *(const bf16x8*)(qwb + (16 * orr + l15) * 64 + 32 + 8 * l4);
      f32x4 acc;
#pragma unroll
      for (int r = 0; r < 4; ++r) acc[r] = qbias[16 * orr + 4 * l4 + r];
      acc = MFMA(a0, xz0, acc);
      acc = MFMA(a1, xz1, acc);
      float e0 = __expf(acc[0]), e1 = __expf(acc[1]);
      float e2 = __expf(acc[2]), e3 = __expf(acc[3]);
      zs += (e0 + e1) + (e2 + e3);
      pzpk[orr][0] = pack2bf(e0, e1);
      pzpk[orr][1] = pack2bf(e2, e3);
    }
    zs += __shfl_xor(zs, 16, 64);
    zs += __shfl_xor(zs, 32, 64);
    invz = 1.f / zs;
  }
  __syncthreads();   // all xb reads done; union buffer becomes o-tile

  // ---- oT = vT @ e^T, scaled by invs[tt] at pack -> ob[t][48h+dloc] ----
  {
    bf16x8 Bp[4][2];
#pragma unroll
    for (int tt = 0; tt < 4; ++tt) {
      Bp[tt][0] = repack(ppk[0][tt][0], ppk[0][tt][1], ppk[1][tt][0], ppk[1][tt][1], srcA, srcB, hi);
      Bp[tt][1] = repack(ppk[2][tt][0], ppk[2][tt][1], ppk[3][tt][0], ppk[3][tt][1], srcA, srcB, hi);
    }
#pragma unroll
    for (int dr = 0; dr < 3; ++dr) {
      bf16x8 A0 = repack(vpk[0][dr][0], vpk[0][dr][1], vpk[1][dr][0], vpk[1][dr][1], srcA, srcB, hi);
      bf16x8 A1 = repack(vpk[2][dr][0], vpk[2][dr][1], vpk[3][dr][0], vpk[3][dr][1], srcA, srcB, hi);
      __builtin_amdgcn_s_setprio(1);
#pragma unroll
      for (int tt = 0; tt < 4; ++tt) {
        f32x4 acc = (f32x4)0.f;
        acc = MFMA(A0, Bp[tt][0], acc);
        acc = MFMA(A1, Bp[tt][1], acc);
        const float iv = invs[tt];     // col t = 16tt+l15 -> this lane's sum
        const int row = 16 * tt + l15;
        const int col = 48 * h + 16 * dr + 4 * l4;
        *(unsigned*)(ob_ + row * 400 + col * 2)     = pack2bf(acc[0] * iv, acc[1] * iv);
        *(unsigned*)(ob_ + row * 400 + col * 2 + 4) = pack2bf(acc[2] * iv, acc[3] * iv);
      }
      __builtin_amdgcn_s_setprio(0);
    }
  }
  __syncthreads();

  // ---- outT[co][t] = WoT2 @ o_all (K=192); freqT = ctx @ ez; combine ----
  {
    f32x4 ot[4], ft[4];
#pragma unroll
    for (int kr = 0; kr < 4; ++kr) { ot[kr] = (f32x4)0.f; ft[kr] = (f32x4)0.f; }
    __builtin_amdgcn_s_setprio(1);
#pragma unroll
    for (int ks = 0; ks < 6; ++ks) {
      bf16x8 bo = *(const bf16x8*)(ob_ + (16 * w + l15) * 400 + 64 * ks + 16 * l4);
#pragma unroll
      for (int kr = 0; kr < 4; ++kr) {
        bf16x8 a = *(const bf16x8*)(WoT2 + (16 * kr + l15) * 192 + 32 * ks + 8 * l4);
        ot[kr] = MFMA(a, bo, ot[kr]);
      }
    }
    {
      bf16x8 Bz0 = repack(pzpk[0][0], pzpk[0][1], pzpk[1][0], pzpk[1][1], srcA, srcB, hi);
      bf16x8 Bz1 = repack(pzpk[2][0], pzpk[2][1], pzpk[3][0], pzpk[3][1], srcA, srcB, hi);
      const short* cb = ctxb16 + ((size_t)b << 12);
#pragma unroll
      for (int kr = 0; kr < 4; ++kr) {
        bf16x8 a0 = *(const bf16x8*)(cb + (16 * kr + l15) * 64 + 8 * l4);
        bf16x8 a1 = *(const bf16x8*)(cb + (16 * kr + l15) * 64 + 32 + 8 * l4);
        ft[kr] = MFMA(a0, Bz0, ft[kr]);
        ft[kr] = MFMA(a1, Bz1, ft[kr]);
      }
    }
    __builtin_amdgcn_s_setprio(0);
    const int t = 16 * w + l15;
    const size_t nbase = (size_t)((y0 + (t >> 3)) * 256 + x0 + (t & 7));
    float* og = out + ((size_t)b << 22);
#pragma unroll
    for (int kr = 0; kr < 4; ++kr)
#pragma unroll
      for (int r = 0; r < 4; ++r) {
        const int co = 16 * kr + 4 * l4 + r;
        og[((size_t)co << 16) + nbase] =
            ot[kr][r] * dw[2 * co] + ft[kr][r] * invz * dw[2 * co + 1];
      }
  }
}

// ========== FMAM single-pass: ctx partials + esum (no-max softmax) =========
// r10 config (chunk 256, grid 512, bf16 cred); chunk partials now bf16 too.
__global__ __launch_bounds__(256) void fmam_ctx1(
    const float* __restrict__ x, const short* __restrict__ fwb,
    const float* __restrict__ fb, short* __restrict__ cp16,
    float* __restrict__ epart)
{
  __shared__ short cred16[4][64 * 68];   // [wave][o*68 + c] bf16
  __shared__ float ered[4][64];
  const int tid = threadIdx.x, lane = tid & 63, w = tid >> 6;
  const int l15 = lane & 15, l4 = lane >> 4;
  const int srcA = l15 + 32 * (l4 & 1), srcB = srcA + 16;
  const bool hi = (l4 & 2) != 0;
  const int chunk = blockIdx.x, b = blockIdx.y;
  const float* xg = x + ((size_t)b << 22);
  const int n0 = (chunk << 8) + (w << 6);

  bf16x8 Bfw[4][2];
#pragma unroll
  for (int ct = 0; ct < 4; ++ct)
#pragma unroll
    for (int ks = 0; ks < 2; ++ks)
      Bfw[ct][ks] = *(const bf16x8*)(fwb + (16 * ct + l15) * 64 + 32 * ks + 8 * l4);
  float fbl[4];
#pragma unroll
  for (int ct = 0; ct < 4; ++ct) fbl[ct] = fb[16 * ct + l15];

  f32x4 acc[4][4];
#pragma unroll
  for (int i = 0; i < 4; ++i)
#pragma unroll
    for (int j = 0; j < 4; ++j) acc[i][j] = (f32x4)0.f;
  float esum[4] = {0.f, 0.f, 0.f, 0.f};

#pragma unroll
  for (int ns = 0; ns < 2; ++ns) {
    const int nb = n0 + 32 * ns;
    bf16x8 axT[2][2];
#pragma unroll
    for (int rt = 0; rt < 2; ++rt)
#pragma unroll
      for (int ks = 0; ks < 2; ++ks)
        axT[rt][ks] = load_xfrag(xg, 32 * ks + 8 * l4, nb + 16 * rt + l15);
    unsigned pl[4][2][2];
#pragma unroll
    for (int rt = 0; rt < 2; ++rt)
#pragma unroll
      for (int ct = 0; ct < 4; ++ct) {
        f32x4 yt = (f32x4)(fbl[ct]);
        yt = MFMA(axT[rt][0], Bfw[ct][0], yt);
        yt = MFMA(axT[rt][1], Bfw[ct][1], yt);
        float e0 = __expf(yt[0]), e1 = __expf(yt[1]);
        float e2 = __expf(yt[2]), e3 = __expf(yt[3]);
        esum[ct] += (e0 + e1) + (e2 + e3);
        pl[ct][rt][0] = pack2bf(e0, e1);
        pl[ct][rt][1] = pack2bf(e2, e3);
      }
    bf16x8 axc[4];
#pragma unroll
    for (int rt2 = 0; rt2 < 4; ++rt2) {
      const float* xr = xg + ((size_t)(16 * rt2 + l15) << 16) + nb + 8 * l4;
      const float4 a4 = *(const float4*)xr;
      const float4 b4 = *(const float4*)(xr + 4);
      bf16x8 f;
      f[0] = f2bf(a4.x); f[1] = f2bf(a4.y); f[2] = f2bf(a4.z); f[3] = f2bf(a4.w);
      f[4] = f2bf(b4.x); f[5] = f2bf(b4.y); f[6] = f2bf(b4.z); f[7] = f2bf(b4.w);
      axc[rt2] = f;
    }
#pragma unroll
    for (int ct = 0; ct < 4; ++ct) {
      bf16x8 Bp = repack(pl[ct][0][0], pl[ct][0][1], pl[ct][1][0], pl[ct][1][1],
                         srcA, srcB, hi);
#pragma unroll
      for (int rt2 = 0; rt2 < 4; ++rt2)
        acc[rt2][ct] = MFMA(axc[rt2], Bp, acc[rt2][ct]);
    }
  }
#pragma unroll
  for (int ct = 0; ct < 4; ++ct) {
    esum[ct] += __shfl_xor(esum[ct], 16, 64);
    esum[ct] += __shfl_xor(esum[ct], 32, 64);
  }
  if (l4 == 0) {
#pragma unroll
    for (int ct = 0; ct < 4; ++ct) ered[w][16 * ct + l15] = esum[ct];
  }
#pragma unroll
  for (int ct = 0; ct < 4; ++ct)
#pragma unroll
    for (int rt2 = 0; rt2 < 4; ++rt2) {
      uint2 pr;
      pr.x = pack2bf(acc[rt2][ct][0], acc[rt2][ct][1]);
      pr.y = pack2bf(acc[rt2][ct][2], acc[rt2][ct][3]);
      *(uint2*)&cred16[w][(16 * ct + l15) * 68 + 16 * rt2 + 4 * l4] = pr;
    }
  __syncthreads();
  short* cp = cp16 + ((((size_t)b << 8) + chunk) << 12);
  for (int i = tid; i < 4096; i += 256) {
    const int o = i >> 6, c = i & 63;
    const int li = o * 68 + c;
    cp[i] = f2bf((bf2f(cred16[0][li]) + bf2f(cred16[1][li])) +
                 (bf2f(cred16[2][li]) + bf2f(cred16[3][li])));
  }
  if (tid < 64)
    epart[(((b << 8) + chunk) << 6) + tid] =
        (ered[0][tid] + ered[1][tid]) + (ered[2][tid] + ered[3][tid]);
}

// ====== reduce pass 1: 512 blocks, each sums 64 chunks for one (b,o) ======
__global__ __launch_bounds__(256) void fmam_red1(
    const short* __restrict__ cp16, const float* __restrict__ epart,
    float* __restrict__ ctxq, float* __restrict__ esumq)
{
  __shared__ float red[4][64];
  const int bid = blockIdx.x;          // 512 = 128 bo x 4 quarters
  const int bo = bid >> 2, q = bid & 3;
  const int b = bo >> 6, o = bo & 63;
  const int tid = threadIdx.x;
  const int c = tid & 63, sub = tid >> 6;
  float s = 0.f;
  const int ch0 = q * 64 + sub * 16;
  for (int ch = ch0; ch < ch0 + 16; ++ch)
    s += bf2f(cp16[((((size_t)b << 8) + ch) << 12) + (o << 6) + c]);
  red[sub][c] = s;
  if (sub == 1) {   // wave 1 also reduces the 64 esum partials of this quarter
    float e = epart[((((size_t)b << 8) + q * 64 + c) << 6) + o];
#pragma unroll
    for (int m = 1; m <= 32; m <<= 1) e += __shfl_xor(e, m, 64);
    if (c == 0) esumq[bid] = e;
  }
  __syncthreads();
  if (tid < 64)
    ctxq[(bid << 6) + tid] =
        (red[0][tid] + red[1][tid]) + (red[2][tid] + red[3][tid]);
}

// ====== reduce pass 2: 128 blocks x 64 thr -> normalized ctx bf16 =========
__global__ void fmam_red2(const float* __restrict__ ctxq,
                          const float* __restrict__ esumq,
                          short* __restrict__ ctxb16)
{
  const int bo = blockIdx.x;           // b*64 + o
  const int c = threadIdx.x;           // 64
  const float et = (esumq[bo * 4] + esumq[bo * 4 + 1]) +
                   (esumq[bo * 4 + 2] + esumq[bo * 4 + 3]);
  const float v = (ctxq[((bo * 4) << 6) + c] + ctxq[((bo * 4 + 1) << 6) + c]) +
                  (ctxq[((bo * 4 + 2) << 6) + c] + ctxq[((bo * 4 + 3) << 6) + c]);
  ctxb16[(bo << 6) + c] = f2bf(v / et);   // ctx_g[b][o][c]
}

// ===========================================================================
extern "C" void kernel_launch(void* const* d_in, const int* in_sizes, int n_in,
                              void* d_out, int out_size, void* d_ws, size_t ws_size,
                              hipStream_t stream) {
  const float* x  = (const float*)d_in[0];
  const float* Wq = (const float*)d_in[1];
  const float* Wk = (const float*)d_in[2];
  const float* Wv = (const float*)d_in[3];
  const float* Wo = (const float*)d_in[4];
  const float* qw = (const float*)d_in[7];
  const float* qb = (const float*)d_in[8];
  const float* fw = (const float*)d_in[9];
  const float* fb = (const float*)d_in[10];
  const float* dw = (const float*)d_in[11];
  float* out = (float*)d_out;

  float* ws = (float*)d_ws;
  short* cp16  = (short*)ws;                 // 2*256*4096 bf16 = 4MB
  float* epart = ws + 1048576;               // after 4MB: 2*256*64 f32 = 128KB
  float* ctxq  = epart + 32768;              // 512*64 f32 = 128KB
  float* esumq = ctxq + 32768;               // 512 f32
  short* wbuf  = (short*)(esumq + 512);
  short* Wt3  = wbuf;                        // 24576
  short* Wvb  = Wt3 + 24576;                 // 12288
  short* WoT2 = Wvb + 12288;                 // 12288
  short* fwb  = WoT2 + 12288;                // 4096
  short* qwb  = fwb + 4096;                  // 4096
  short* ctxb16 = qwb + 4096;                // 8192

  hipLaunchKernelGGL(prep_w, dim3(96), dim3(256), 0, stream,
                     Wq, Wk, Wv, Wo, fw, qw, Wt3, Wvb, WoT2, fwb, qwb);
  hipLaunchKernelGGL(fmam_ctx1, dim3(256, 2), dim3(256), 0, stream,
                     x, fwb, fb, cp16, epart);
  hipLaunchKernelGGL(fmam_red1, dim3(512), dim3(256), 0, stream,
                     cp16, epart, ctxq, esumq);
  hipLaunchKernelGGL(fmam_red2, dim3(128), dim3(64), 0, stream,
                     ctxq, esumq, ctxb16);
  hipLaunchKernelGGL(attn_fused, dim3(2048), dim3(256), 0, stream,
                     x, Wt3, Wvb, WoT2, qwb, qb, ctxb16, dw, out);
}